// Round 6
// baseline (453.321 us; speedup 1.0000x reference)
//
#include <hip/hip_runtime.h>

// Inverse 2D DWT, single level, fused column+row synthesis. FP32 throughout.
// One wave per 8-row strip, rolling 3-row register window, horizontal halos
// via cross-lane shuffle of the vertical-synthesis results.
//
// Rounds 2-5 lesson: per-wave MLP, oversubscription, XCD swizzle and store
// line-coverage are ALL neutral at ~150us = 3.1 TB/s, exactly half of
// fill/copy BW (6.3-6.5 TB/s). Diagnosis: HBM channel camping. The 4 input
// streams and 256 images are 2^26 B apart (congruent mod channel interleave),
// strips are 8 KB apart (multiple of the channel period), and strips march in
// lockstep -> the instantaneous address set hits only a small subset of HBM
// channels at any moment. Fix: rotate each strip's row-processing order by a
// per-strip phase q=(sx+bc)&7, so co-resident strips cover ALL row phases
// (hence all channels) at every instant. Costs one extra 2-row window reload
// per strip at the rotation wrap.
//
// out[2i+py][2j+px] = sum_{dy,dx in {-1,0,1}}
//   wh[py][dy]*wh[px][dx]*ss + wg[py][dy]*wh[px][dx]*sd
// + wh[py][dy]*wg[px][dx]*ds + wg[py][dy]*wg[px][dx]*dd
// with wh[0] = (h4,h2,h0), wh[1] = (h5,h3,h1) over dy=(-1,0,+1); reflect pad 1.

typedef float float4v __attribute__((ext_vector_type(4)));

constexpr int Hc = 256;
constexpr int Wc = 256;
constexpr int ROWS = 8;   // rows per wave strip
constexpr int WPB  = 4;   // waves per block

__global__ __launch_bounds__(256) void idwt_kernel(
    const float* __restrict__ ss, const float* __restrict__ sd,
    const float* __restrict__ ds, const float* __restrict__ dd,
    const float* __restrict__ hf, const float* __restrict__ gf,
    float* __restrict__ out)
{
    const int lane = threadIdx.x;                 // 0..63
    const int wid  = threadIdx.y;                 // 0..WPB-1
    const int sx   = blockIdx.x * WPB + wid;      // strip index 0..31
    const int bc   = blockIdx.y;                  // 0..B*C-1
    const int i0   = sx * ROWS;                   // first row of this strip
    const int q    = (sx + bc) & (ROWS - 1);      // row phase rotation

    const float h0 = hf[0], h1 = hf[1], h2 = hf[2];
    const float h3 = hf[3], h4 = hf[4], h5 = hf[5];
    const float g0 = gf[0], g1 = gf[1], g2 = gf[2];
    const float g3 = gf[3], g4 = gf[4], g5 = gf[5];

    const size_t off = (size_t)bc * (Hc * Wc);
    const int j0 = lane * 4;
    const float* pss = ss + off + j0;
    const float* psd = sd + off + j0;
    const float* pds = ds + off + j0;
    const float* pdd = dd + off + j0;

    auto ld = [&](const float* p, int r) -> float4v {
        return *reinterpret_cast<const float4v*>(p + (size_t)r * Wc);
    };

    const int W2 = 2 * Wc;
    float* obase = out + (size_t)bc * (2 * Hc) * W2 + 8 * lane;

    // horizontal reflect at image edges:
    //   col -1 -> col 1 (lane 0: w[1]); col Wc -> col Wc-2 (lane 63: w[2])
    auto left = [&](const float4v& w) -> float {
        float l = __shfl_up(w[3], 1);
        return (lane == 0) ? w[1] : l;
    };
    auto right = [&](const float4v& w) -> float {
        float rr = __shfl_down(w[0], 1);
        return (lane == 63) ? w[2] : rr;
    };

    // rolling 3-row windows: *_m = row i-1, *_c = row i, *_p = row i+1
    float4v s_m, s_c, t_m, t_c, u_m, u_c, v_m, v_c;

    #pragma unroll
    for (int rr = 0; rr < ROWS; ++rr) {
        const int r = (q + rr) & (ROWS - 1);   // rotated row order
        const int i = i0 + r;

        // (re)load the 3-row window at the start and at the rotation wrap;
        // otherwise it was shifted by the previous iteration. Wave-uniform.
        if (rr == 0 || r == 0) {
            const int rm = (i == 0) ? 1 : i - 1;   // reflect-1 at top
            s_m = ld(pss, rm); s_c = ld(pss, i);
            t_m = ld(psd, rm); t_c = ld(psd, i);
            u_m = ld(pds, rm); u_c = ld(pds, i);
            v_m = ld(pdd, rm); v_c = ld(pdd, i);
        }
        const int rn = (i + 1 < Hc) ? i + 1 : Hc - 2;  // reflect-1 at bottom
        const float4v s_p = ld(pss, rn);
        const float4v t_p = ld(psd, rn);
        const float4v u_p = ld(pds, rn);
        const float4v v_p = ld(pdd, rn);

        // vertical (column) synthesis for this wave's 4 columns
        float4v vs0, vs1, vd0, vd1;
        #pragma unroll
        for (int k = 0; k < 4; ++k) {
            vs0[k] = h4*s_m[k] + h2*s_c[k] + h0*s_p[k] + g4*t_m[k] + g2*t_c[k] + g0*t_p[k];
            vs1[k] = h5*s_m[k] + h3*s_c[k] + h1*s_p[k] + g5*t_m[k] + g3*t_c[k] + g1*t_p[k];
            vd0[k] = h4*u_m[k] + h2*u_c[k] + h0*u_p[k] + g4*v_m[k] + g2*v_c[k] + g0*v_p[k];
            vd1[k] = h5*u_m[k] + h3*u_c[k] + h1*u_p[k] + g5*v_m[k] + g3*v_c[k] + g1*v_p[k];
        }

        // 6-wide horizontal windows via shuffle (static indices only)
        const float a [6] = { left(vs0), vs0[0], vs0[1], vs0[2], vs0[3], right(vs0) };
        const float b [6] = { left(vd0), vd0[0], vd0[1], vd0[2], vd0[3], right(vd0) };
        const float c2[6] = { left(vs1), vs1[0], vs1[1], vs1[2], vs1[3], right(vs1) };
        const float d2[6] = { left(vd1), vd1[0], vd1[1], vd1[2], vd1[3], right(vd1) };

        // horizontal (row) synthesis: 2 output rows x 8 output cols
        float4v o00, o01, o10, o11;
        #pragma unroll
        for (int t = 0; t < 4; ++t) {
            const float e0 = h4*a [t] + h2*a [t+1] + h0*a [t+2] + g4*b [t] + g2*b [t+1] + g0*b [t+2];
            const float e1 = h5*a [t] + h3*a [t+1] + h1*a [t+2] + g5*b [t] + g3*b [t+1] + g1*b [t+2];
            const float f0 = h4*c2[t] + h2*c2[t+1] + h0*c2[t+2] + g4*d2[t] + g2*d2[t+1] + g0*d2[t+2];
            const float f1 = h5*c2[t] + h3*c2[t+1] + h1*c2[t+2] + g5*d2[t] + g3*d2[t+1] + g1*d2[t+2];
            if (t < 2) {
                o00[2*t]     = e0; o00[2*t+1]     = e1;
                o10[2*t]     = f0; o10[2*t+1]     = f1;
            } else {
                o01[2*(t-2)] = e0; o01[2*(t-2)+1] = e1;
                o11[2*(t-2)] = f0; o11[2*(t-2)+1] = f1;
            }
        }

        float* orow0 = obase + (size_t)(2 * i) * W2;
        float* orow1 = orow0 + W2;
        *reinterpret_cast<float4v*>(orow0)     = o00;
        *reinterpret_cast<float4v*>(orow0 + 4) = o01;
        *reinterpret_cast<float4v*>(orow1)     = o10;
        *reinterpret_cast<float4v*>(orow1 + 4) = o11;

        // shift rolling windows (dead at a wrap, where the reload overwrites)
        s_m = s_c; s_c = s_p;
        t_m = t_c; t_c = t_p;
        u_m = u_c; u_c = u_p;
        v_m = v_c; v_c = v_p;
    }
}

extern "C" void kernel_launch(void* const* d_in, const int* in_sizes, int n_in,
                              void* d_out, int out_size, void* d_ws, size_t ws_size,
                              hipStream_t stream) {
    const float* ss = (const float*)d_in[0];
    const float* sd = (const float*)d_in[1];
    const float* ds = (const float*)d_in[2];
    const float* dd = (const float*)d_in[3];
    const float* hf = (const float*)d_in[4];
    const float* gf = (const float*)d_in[5];
    float* out = (float*)d_out;

    const int BC = in_sizes[0] / (Hc * Wc);   // B*C = 256
    dim3 block(64, WPB);                       // 1 wave x 4 strips per block
    dim3 grid(Hc / (ROWS * WPB), BC);          // (8, 256)
    idwt_kernel<<<grid, block, 0, stream>>>(ss, sd, ds, dd, hf, gf, out);
}

// Round 7
// 444.651 us; speedup vs baseline: 1.0195x; 1.0195x over previous
//
#include <hip/hip_runtime.h>

// Inverse 2D DWT, single level, fused column+row synthesis. FP32 throughout.
// One wave per 8-row strip. R7 experiment: WHOLE-STRIP BURST PRELOAD.
// R1-R6 established: traffic is minimal and ~149us = 3.1 TB/s regardless of
// MLP, occupancy, store pattern, or phase -- half of fill/copy BW. Remaining
// structural difference vs a copy: per-stream sequential burst length. R1-R6
// issued 4x 1KB (one row per stream) per iteration; the next row of a stream
// came ~10^3-10^4 cycles later -> DRAM sees random 1KB granules (~50% page
// efficiency). Here each wave preloads its whole strip as 4 per-stream
// CONTIGUOUS bursts (10 rows x 1KB back-to-back per stream, 40 loads total,
// all in flight; vmcnt limit is 63). sched_barrier(0) pins the schedule so
// the compiler cannot sink loads back to their uses.
// out[2i+py][2j+px] = sum_{dy,dx in {-1,0,1}}
//   wh[py][dy]*wh[px][dx]*ss + wg[py][dy]*wh[px][dx]*sd
// + wh[py][dy]*wg[px][dx]*ds + wg[py][dy]*wg[px][dx]*dd
// with wh[0] = (h4,h2,h0), wh[1] = (h5,h3,h1) over dy=(-1,0,+1); reflect pad 1.

typedef float float4v __attribute__((ext_vector_type(4)));

constexpr int Hc = 256;
constexpr int Wc = 256;
constexpr int ROWS = 8;   // rows per wave strip
constexpr int WPB  = 4;   // waves per block

__global__ __launch_bounds__(256) void idwt_kernel(
    const float* __restrict__ ss, const float* __restrict__ sd,
    const float* __restrict__ ds, const float* __restrict__ dd,
    const float* __restrict__ hf, const float* __restrict__ gf,
    float* __restrict__ out)
{
    const int lane = threadIdx.x;                 // 0..63
    const int wid  = threadIdx.y;                 // 0..WPB-1
    const int sx   = blockIdx.x * WPB + wid;      // strip index 0..31
    const int bc   = blockIdx.y;                  // 0..B*C-1
    const int i0   = sx * ROWS;                   // first row of this strip

    const float h0 = hf[0], h1 = hf[1], h2 = hf[2];
    const float h3 = hf[3], h4 = hf[4], h5 = hf[5];
    const float g0 = gf[0], g1 = gf[1], g2 = gf[2];
    const float g3 = gf[3], g4 = gf[4], g5 = gf[5];

    const size_t off = (size_t)bc * (Hc * Wc);
    const int j0 = lane * 4;
    const float* pss = ss + off + j0;
    const float* psd = sd + off + j0;
    const float* pds = ds + off + j0;
    const float* pdd = dd + off + j0;

    auto ld = [&](const float* p, int r) -> float4v {
        return *reinterpret_cast<const float4v*>(p + (size_t)r * Wc);
    };

    // ---- whole-strip preload: per-stream contiguous bursts ----
    // S[0] = row i0-1 (reflect), S[1+k] = row i0+k (k=0..7), S[9] = row i0+8
    // (reflect at bottom). All indices compile-time under full unroll.
    const int rm = (i0 == 0) ? 1 : i0 - 1;
    const int rp = (i0 + ROWS < Hc) ? i0 + ROWS : Hc - 2;

    float4v S[ROWS + 2], T[ROWS + 2], U[ROWS + 2], V[ROWS + 2];
    S[0] = ld(pss, rm);
    #pragma unroll
    for (int k = 0; k < ROWS; ++k) S[1 + k] = ld(pss, i0 + k);   // 8KB burst
    S[ROWS + 1] = ld(pss, rp);
    T[0] = ld(psd, rm);
    #pragma unroll
    for (int k = 0; k < ROWS; ++k) T[1 + k] = ld(psd, i0 + k);
    T[ROWS + 1] = ld(psd, rp);
    U[0] = ld(pds, rm);
    #pragma unroll
    for (int k = 0; k < ROWS; ++k) U[1 + k] = ld(pds, i0 + k);
    U[ROWS + 1] = ld(pds, rp);
    V[0] = ld(pdd, rm);
    #pragma unroll
    for (int k = 0; k < ROWS; ++k) V[1 + k] = ld(pdd, i0 + k);
    V[ROWS + 1] = ld(pdd, rp);

    // Pin the schedule: no sinking loads below / hoisting compute above.
    __builtin_amdgcn_sched_barrier(0);

    const int W2 = 2 * Wc;
    float* obase = out + (size_t)bc * (2 * Hc) * W2 + 8 * lane;

    // horizontal reflect at image edges:
    //   col -1 -> col 1 (lane 0: w[1]); col Wc -> col Wc-2 (lane 63: w[2])
    auto left = [&](const float4v& w) -> float {
        float l = __shfl_up(w[3], 1);
        return (lane == 0) ? w[1] : l;
    };
    auto right = [&](const float4v& w) -> float {
        float rr = __shfl_down(w[0], 1);
        return (lane == 63) ? w[2] : rr;
    };

    #pragma unroll
    for (int r = 0; r < ROWS; ++r) {
        const int i = i0 + r;

        // vertical (column) synthesis from preloaded rows i-1, i, i+1
        float4v vs0, vs1, vd0, vd1;
        #pragma unroll
        for (int k = 0; k < 4; ++k) {
            vs0[k] = h4*S[r][k] + h2*S[r+1][k] + h0*S[r+2][k] + g4*T[r][k] + g2*T[r+1][k] + g0*T[r+2][k];
            vs1[k] = h5*S[r][k] + h3*S[r+1][k] + h1*S[r+2][k] + g5*T[r][k] + g3*T[r+1][k] + g1*T[r+2][k];
            vd0[k] = h4*U[r][k] + h2*U[r+1][k] + h0*U[r+2][k] + g4*V[r][k] + g2*V[r+1][k] + g0*V[r+2][k];
            vd1[k] = h5*U[r][k] + h3*U[r+1][k] + h1*U[r+2][k] + g5*V[r][k] + g3*V[r+1][k] + g1*V[r+2][k];
        }

        // 6-wide horizontal windows via shuffle (static indices only)
        const float a [6] = { left(vs0), vs0[0], vs0[1], vs0[2], vs0[3], right(vs0) };
        const float b [6] = { left(vd0), vd0[0], vd0[1], vd0[2], vd0[3], right(vd0) };
        const float c2[6] = { left(vs1), vs1[0], vs1[1], vs1[2], vs1[3], right(vs1) };
        const float d2[6] = { left(vd1), vd1[0], vd1[1], vd1[2], vd1[3], right(vd1) };

        // horizontal (row) synthesis: 2 output rows x 8 output cols
        float4v o00, o01, o10, o11;
        #pragma unroll
        for (int t = 0; t < 4; ++t) {
            const float e0 = h4*a [t] + h2*a [t+1] + h0*a [t+2] + g4*b [t] + g2*b [t+1] + g0*b [t+2];
            const float e1 = h5*a [t] + h3*a [t+1] + h1*a [t+2] + g5*b [t] + g3*b [t+1] + g1*b [t+2];
            const float f0 = h4*c2[t] + h2*c2[t+1] + h0*c2[t+2] + g4*d2[t] + g2*d2[t+1] + g0*d2[t+2];
            const float f1 = h5*c2[t] + h3*c2[t+1] + h1*c2[t+2] + g5*d2[t] + g3*d2[t+1] + g1*d2[t+2];
            if (t < 2) {
                o00[2*t]     = e0; o00[2*t+1]     = e1;
                o10[2*t]     = f0; o10[2*t+1]     = f1;
            } else {
                o01[2*(t-2)] = e0; o01[2*(t-2)+1] = e1;
                o11[2*(t-2)] = f0; o11[2*(t-2)+1] = f1;
            }
        }

        float* orow0 = obase + (size_t)(2 * i) * W2;
        float* orow1 = orow0 + W2;
        *reinterpret_cast<float4v*>(orow0)     = o00;
        *reinterpret_cast<float4v*>(orow0 + 4) = o01;
        *reinterpret_cast<float4v*>(orow1)     = o10;
        *reinterpret_cast<float4v*>(orow1 + 4) = o11;
    }
}

extern "C" void kernel_launch(void* const* d_in, const int* in_sizes, int n_in,
                              void* d_out, int out_size, void* d_ws, size_t ws_size,
                              hipStream_t stream) {
    const float* ss = (const float*)d_in[0];
    const float* sd = (const float*)d_in[1];
    const float* ds = (const float*)d_in[2];
    const float* dd = (const float*)d_in[3];
    const float* hf = (const float*)d_in[4];
    const float* gf = (const float*)d_in[5];
    float* out = (float*)d_out;

    const int BC = in_sizes[0] / (Hc * Wc);   // B*C = 256
    dim3 block(64, WPB);                       // 1 wave x 4 strips per block
    dim3 grid(Hc / (ROWS * WPB), BC);          // (8, 256)
    idwt_kernel<<<grid, block, 0, stream>>>(ss, sd, ds, dd, hf, gf, out);
}